// Round 2
// baseline (341.831 us; speedup 1.0000x reference)
//
#include <hip/hip_runtime.h>
#include <hip/hip_cooperative_groups.h>

namespace cg = cooperative_groups;

#define Hd 512
#define N2d 16
#define Rd 32
#define Ld 4096
#define NCHUNK 128
#define CLEN (Ld / NCHUNK)   // 32
#define NCH (Hd * N2d)       // 8192 chains
#define PBLK 512             // physical blocks (2/CU guaranteed residency)
#define VBLK 1024            // virtual blocks for phases B/D

// ---------------------------------------------------------------------------
// Kernel 0: transpose dt_w[H][R] -> dt_wT[R][H] for coalesced einsum2 loads.
// ---------------------------------------------------------------------------
__global__ __launch_bounds__(256) void k_tw(const float* __restrict__ dt_w,
                                            float* __restrict__ dt_wT) {
    int idx = blockIdx.x * 256 + threadIdx.x;   // 0..16383
    int r = idx >> 9;
    int h = idx & 511;
    dt_wT[idx] = dt_w[h * Rd + r];
}

// ---------------------------------------------------------------------------
// Per-thread constant setup: 4 consecutive n of one h. fast == true when Are
// uniform and Aim arithmetic across the 4 (true for S4D init A = -1 + i*n).
// ---------------------------------------------------------------------------
__device__ __forceinline__ bool load_consts4(const float* A_log, const float* A_im,
        const float* B_param, int hnb,
        float* Are, float* Aim, float* BAr, float* BAi) {
    #pragma unroll
    for (int j = 0; j < 4; ++j) {
        int hn = hnb + j;
        Are[j] = -__expf(A_log[hn]);
        Aim[j] = A_im[hn];
        float Bre = B_param[2 * hn];
        float Bim = B_param[2 * hn + 1];
        float inv = __builtin_amdgcn_rcpf(Are[j] * Are[j] + Aim[j] * Aim[j]);
        BAr[j] = (Bre * Are[j] + Bim * Aim[j]) * inv;   // Bc*conj(A)/|A|^2
        BAi[j] = (Bim * Are[j] - Bre * Aim[j]) * inv;
    }
    float d1 = Aim[1] - Aim[0], d2 = Aim[2] - Aim[1], d3 = Aim[3] - Aim[2];
    return (Are[1] == Are[0]) && (Are[2] == Are[0]) && (Are[3] == Are[0]) &&
           (d1 == d2) && (d2 == d3);
}

// ---------------------------------------------------------------------------
// Phase A: dt = softplus(u@xprojT@dtwT + b); block b owns 8 rows of u.
// ---------------------------------------------------------------------------
__device__ __forceinline__ void phaseA(const float* __restrict__ u,
        const float* __restrict__ xproj_w, const float* __restrict__ dt_wT,
        const float* __restrict__ dt_b, float2* __restrict__ du,
        int b, int t, float (*u_s)[Hd], float (*dtu_s)[Rd]) {
    const int l0 = b * 8;
    #pragma unroll
    for (int i = 0; i < 16; ++i) {
        int idx = t + i * 256;
        ((float*)u_s)[idx] = u[l0 * Hd + idx];
    }
    __syncthreads();
    const int r = t >> 3;
    const int j = t & 7;
    float part[8];
    #pragma unroll
    for (int l = 0; l < 8; ++l) part[l] = 0.f;
    for (int k = 0; k < 64; ++k) {
        float w = xproj_w[r * Hd + k * 8 + j];
        #pragma unroll
        for (int l = 0; l < 8; ++l) part[l] = fmaf(u_s[l][k * 8 + j], w, part[l]);
    }
    #pragma unroll
    for (int off = 1; off < 8; off <<= 1) {
        #pragma unroll
        for (int l = 0; l < 8; ++l) part[l] += __shfl_xor(part[l], off);
    }
    if (j == 0) {
        #pragma unroll
        for (int l = 0; l < 8; ++l) dtu_s[l][r] = part[l];
    }
    __syncthreads();
    #pragma unroll
    for (int hb = 0; hb < 2; ++hb) {
        int h = hb * 256 + t;
        float bias = dt_b[h];
        float acc[8];
        #pragma unroll
        for (int l = 0; l < 8; ++l) acc[l] = bias;
        for (int rr = 0; rr < Rd; ++rr) {
            float w = dt_wT[rr * Hd + h];
            #pragma unroll
            for (int l = 0; l < 8; ++l) acc[l] = fmaf(dtu_s[l][rr], w, acc[l]);
        }
        #pragma unroll
        for (int l = 0; l < 8; ++l) {
            float x = acc[l];
            float sp = fmaxf(x, 0.f) + log1pf(__expf(-fabsf(x)));  // softplus
            float uv = u_s[l][h];
            float us = uv * __builtin_amdgcn_rcpf(fmaxf(sp, 1e-30f));
            du[(l0 + l) * Hd + h] = make_float2(sp, us);
        }
    }
}

// ---------------------------------------------------------------------------
// Phase B: per-chunk local scan (h0=0) -> P, S. vb = hgroup*128 + chunk.
// ---------------------------------------------------------------------------
__device__ __forceinline__ void phaseB(const float2* __restrict__ du,
        const float* __restrict__ A_log, const float* __restrict__ A_im,
        const float* __restrict__ B_param, float2* __restrict__ Pbuf,
        float2* __restrict__ Sbuf, int vb, int t) {
    const int q = t & 3;
    const int hh = (vb >> 7) * 64 + (t >> 2);
    const int c = vb & 127;
    const int hnb = hh * N2d + q * 4;
    const int lbase = c * CLEN;
    float Are[4], Aim[4], BAr[4], BAi[4];
    const bool fast = load_consts4(A_log, A_im, B_param, hnb, Are, Aim, BAr, BAi);
    float sr[4] = {0.f, 0.f, 0.f, 0.f}, si[4] = {0.f, 0.f, 0.f, 0.f};
    float sdt = 0.f;
    if (fast) {
        const float Are0 = Are[0], Aim0 = Aim[0], dA = Aim[1] - Aim[0];
        #pragma unroll 4
        for (int k = 0; k < CLEN; ++k) {
            float2 d = du[(lbase + k) * Hd + hh];
            float dtv = d.x, us = d.y;
            sdt += dtv;
            float er = __expf(dtv * Are0);
            float s0, c0, sd, cd;
            __sincosf(dtv * Aim0, &s0, &c0);
            __sincosf(dtv * dA, &sd, &cd);
            float ar = er * c0, ai = er * s0;
            #pragma unroll
            for (int jj = 0; jj < 4; ++jj) {
                float gr = fmaf(ar, us, -us);
                float gi = ai * us;
                float nr = fmaf(ar, sr[jj], fmaf(-ai, si[jj], fmaf(gr, BAr[jj], -gi * BAi[jj])));
                float ni = fmaf(ar, si[jj], fmaf( ai, sr[jj], fmaf(gr, BAi[jj],  gi * BAr[jj])));
                sr[jj] = nr; si[jj] = ni;
                if (jj < 3) {
                    float tr = fmaf(ar, cd, -ai * sd);
                    ai = fmaf(ai, cd, ar * sd);
                    ar = tr;
                }
            }
        }
    } else {
        #pragma unroll 4
        for (int k = 0; k < CLEN; ++k) {
            float2 d = du[(lbase + k) * Hd + hh];
            float dtv = d.x, us = d.y;
            sdt += dtv;
            #pragma unroll
            for (int jj = 0; jj < 4; ++jj) {
                float er = __expf(dtv * Are[jj]);
                float s, cc;
                __sincosf(dtv * Aim[jj], &s, &cc);
                float ar = er * cc, ai = er * s;
                float gr = fmaf(ar, us, -us);
                float gi = ai * us;
                float nr = fmaf(ar, sr[jj], fmaf(-ai, si[jj], fmaf(gr, BAr[jj], -gi * BAi[jj])));
                float ni = fmaf(ar, si[jj], fmaf( ai, sr[jj], fmaf(gr, BAi[jj],  gi * BAr[jj])));
                sr[jj] = nr; si[jj] = ni;
            }
        }
    }
    int base = c * NCH + hnb;
    #pragma unroll
    for (int jj = 0; jj < 4; ++jj) {
        float er = __expf(sdt * Are[jj]);
        float s, cc;
        __sincosf(sdt * Aim[jj], &s, &cc);
        Pbuf[base + jj] = make_float2(er * cc, er * s);
        Sbuf[base + jj] = make_float2(sr[jj], si[jj]);
    }
}

// ---------------------------------------------------------------------------
// Phase C: sequential combine over chunks -> per-chunk init state.
// ---------------------------------------------------------------------------
__device__ __forceinline__ void phaseC(const float2* __restrict__ Pbuf,
        const float2* __restrict__ Sbuf, float2* __restrict__ Ibuf, int gidx) {
    float hr = 0.f, hi = 0.f;
    for (int bb = 0; bb < NCHUNK / 8; ++bb) {
        float2 tp[8], ts[8];
        #pragma unroll
        for (int i = 0; i < 8; ++i) {
            tp[i] = Pbuf[(bb * 8 + i) * NCH + gidx];
            ts[i] = Sbuf[(bb * 8 + i) * NCH + gidx];
        }
        #pragma unroll
        for (int i = 0; i < 8; ++i) {
            Ibuf[(bb * 8 + i) * NCH + gidx] = make_float2(hr, hi);
            float nr = fmaf(tp[i].x, hr, fmaf(-tp[i].y, hi, ts[i].x));
            float ni = fmaf(tp[i].x, hi, fmaf( tp[i].y, hr, ts[i].y));
            hr = nr; hi = ni;
        }
    }
}

// ---------------------------------------------------------------------------
// Phase D: re-scan chunks with correct init; emit y.
// ---------------------------------------------------------------------------
__device__ __forceinline__ void phaseD(const float2* __restrict__ du,
        const float* __restrict__ A_log, const float* __restrict__ A_im,
        const float* __restrict__ B_param, const float* __restrict__ C_param,
        const float* __restrict__ Dp, const float2* __restrict__ Ibuf,
        float* __restrict__ out, int vb, int t) {
    const int q = t & 3;
    const int hh = (vb >> 7) * 64 + (t >> 2);
    const int c = vb & 127;
    const int hnb = hh * N2d + q * 4;
    const int lbase = c * CLEN;
    float Are[4], Aim[4], BAr[4], BAi[4], Cre[4], Cim[4];
    const bool fast = load_consts4(A_log, A_im, B_param, hnb, Are, Aim, BAr, BAi);
    #pragma unroll
    for (int jj = 0; jj < 4; ++jj) {
        Cre[jj] = C_param[2 * (hnb + jj)];
        Cim[jj] = C_param[2 * (hnb + jj) + 1];
    }
    const float Dv = Dp[hh];
    float hr[4], hi[4];
    {
        int base = c * NCH + hnb;
        #pragma unroll
        for (int jj = 0; jj < 4; ++jj) {
            float2 h0 = Ibuf[base + jj];
            hr[jj] = h0.x; hi[jj] = h0.y;
        }
    }
    if (fast) {
        const float Are0 = Are[0], Aim0 = Aim[0], dA = Aim[1] - Aim[0];
        #pragma unroll 4
        for (int k = 0; k < CLEN; ++k) {
            int l = lbase + k;
            float2 d = du[l * Hd + hh];
            float dtv = d.x, us = d.y;
            float er = __expf(dtv * Are0);
            float s0, c0, sd, cd;
            __sincosf(dtv * Aim0, &s0, &c0);
            __sincosf(dtv * dA, &sd, &cd);
            float ar = er * c0, ai = er * s0;
            float yv = 0.f;
            #pragma unroll
            for (int jj = 0; jj < 4; ++jj) {
                float gr = fmaf(ar, us, -us);
                float gi = ai * us;
                float nr = fmaf(ar, hr[jj], fmaf(-ai, hi[jj], fmaf(gr, BAr[jj], -gi * BAi[jj])));
                float ni = fmaf(ar, hi[jj], fmaf( ai, hr[jj], fmaf(gr, BAi[jj],  gi * BAr[jj])));
                hr[jj] = nr; hi[jj] = ni;
                yv = fmaf(nr, Cre[jj], fmaf(-ni, Cim[jj], yv));
                if (jj < 3) {
                    float tr = fmaf(ar, cd, -ai * sd);
                    ai = fmaf(ai, cd, ar * sd);
                    ar = tr;
                }
            }
            yv += __shfl_xor(yv, 1);
            yv += __shfl_xor(yv, 2);
            if (q == 0) out[l * Hd + hh] = fmaf(dtv * us, Dv, yv);
        }
    } else {
        #pragma unroll 4
        for (int k = 0; k < CLEN; ++k) {
            int l = lbase + k;
            float2 d = du[l * Hd + hh];
            float dtv = d.x, us = d.y;
            float yv = 0.f;
            #pragma unroll
            for (int jj = 0; jj < 4; ++jj) {
                float er = __expf(dtv * Are[jj]);
                float s, cc;
                __sincosf(dtv * Aim[jj], &s, &cc);
                float ar = er * cc, ai = er * s;
                float gr = fmaf(ar, us, -us);
                float gi = ai * us;
                float nr = fmaf(ar, hr[jj], fmaf(-ai, hi[jj], fmaf(gr, BAr[jj], -gi * BAi[jj])));
                float ni = fmaf(ar, hi[jj], fmaf( ai, hr[jj], fmaf(gr, BAi[jj],  gi * BAr[jj])));
                hr[jj] = nr; hi[jj] = ni;
                yv = fmaf(nr, Cre[jj], fmaf(-ni, Cim[jj], yv));
            }
            yv += __shfl_xor(yv, 1);
            yv += __shfl_xor(yv, 2);
            if (q == 0) out[l * Hd + hh] = fmaf(dtv * us, Dv, yv);
        }
    }
}

// ---------------------------------------------------------------------------
// Fused cooperative kernel: 512 blocks x 256 threads (2 blocks/CU — generous
// margin for the cooperative residency check; VGPR cap 256 so no spill risk).
// Phases B/D each process 2 virtual blocks.
// ---------------------------------------------------------------------------
__global__ __launch_bounds__(256, 2) void k_fused(
        const float* __restrict__ u, const float* __restrict__ xproj_w,
        const float* __restrict__ dt_wT, const float* __restrict__ dt_b,
        const float* __restrict__ A_log, const float* __restrict__ A_im,
        const float* __restrict__ B_param, const float* __restrict__ C_param,
        const float* __restrict__ Dp,
        float2* __restrict__ du, float2* __restrict__ Pbuf,
        float2* __restrict__ Sbuf, float2* __restrict__ Ibuf,
        float* __restrict__ out) {
    cg::grid_group grid = cg::this_grid();
    __shared__ float u_s[8][Hd];
    __shared__ float dtu_s[8][Rd];
    const int t = threadIdx.x;
    const int b = blockIdx.x;

    phaseA(u, xproj_w, dt_wT, dt_b, du, b, t, u_s, dtu_s);
    grid.sync();
    phaseB(du, A_log, A_im, B_param, Pbuf, Sbuf, b, t);
    phaseB(du, A_log, A_im, B_param, Pbuf, Sbuf, b + PBLK, t);
    grid.sync();
    if (b < NCH / 256) phaseC(Pbuf, Sbuf, Ibuf, b * 256 + t);
    grid.sync();
    phaseD(du, A_log, A_im, B_param, C_param, Dp, Ibuf, out, b, t);
    phaseD(du, A_log, A_im, B_param, C_param, Dp, Ibuf, out, b + PBLK, t);
}

// ---------------------------------------------------------------------------
// Standalone fallback kernels (round-0 pipeline, shared device bodies).
// ---------------------------------------------------------------------------
__global__ __launch_bounds__(256) void k_dt(const float* __restrict__ u,
        const float* __restrict__ xproj_w, const float* __restrict__ dt_wT,
        const float* __restrict__ dt_b, float2* __restrict__ du) {
    __shared__ float u_s[8][Hd];
    __shared__ float dtu_s[8][Rd];
    phaseA(u, xproj_w, dt_wT, dt_b, du, blockIdx.x, threadIdx.x, u_s, dtu_s);
}

__global__ __launch_bounds__(256) void k_chunk(const float2* __restrict__ du,
        const float* __restrict__ A_log, const float* __restrict__ A_im,
        const float* __restrict__ B_param,
        float2* __restrict__ Pbuf, float2* __restrict__ Sbuf) {
    phaseB(du, A_log, A_im, B_param, Pbuf, Sbuf,
           blockIdx.y * NCHUNK + blockIdx.x, threadIdx.x);
}

__global__ __launch_bounds__(256) void k_prefix(const float2* __restrict__ Pbuf,
        const float2* __restrict__ Sbuf, float2* __restrict__ Ibuf) {
    phaseC(Pbuf, Sbuf, Ibuf, blockIdx.x * 256 + threadIdx.x);
}

__global__ __launch_bounds__(256) void k_scan(const float2* __restrict__ du,
        const float* __restrict__ A_log, const float* __restrict__ A_im,
        const float* __restrict__ B_param, const float* __restrict__ C_param,
        const float* __restrict__ Dp, const float2* __restrict__ Ibuf,
        float* __restrict__ out) {
    phaseD(du, A_log, A_im, B_param, C_param, Dp, Ibuf, out,
           blockIdx.y * NCHUNK + blockIdx.x, threadIdx.x);
}

extern "C" void kernel_launch(void* const* d_in, const int* in_sizes, int n_in,
                              void* d_out, int out_size, void* d_ws, size_t ws_size,
                              hipStream_t stream) {
    const float* u        = (const float*)d_in[0];
    const float* A_log    = (const float*)d_in[1];
    const float* A_im     = (const float*)d_in[2];
    const float* B_param  = (const float*)d_in[3];
    const float* C_param  = (const float*)d_in[4];
    const float* Dp       = (const float*)d_in[5];
    const float* dt_w     = (const float*)d_in[6];
    const float* dt_b     = (const float*)d_in[7];
    const float* xproj_w  = (const float*)d_in[8];

    // ws: du[L*H f2] | P[NCHUNK*NCH f2] | S[..] | I[..] | dt_wT[R*H f]
    float2* du    = (float2*)d_ws;
    float2* Pbuf  = du + (size_t)Ld * Hd;
    float2* Sbuf  = Pbuf + (size_t)NCHUNK * NCH;
    float2* Ibuf  = Sbuf + (size_t)NCHUNK * NCH;
    float*  dt_wT = (float*)(Ibuf + (size_t)NCHUNK * NCH);
    float*  out   = (float*)d_out;

    k_tw<<<(Rd * Hd) / 256, 256, 0, stream>>>(dt_w, dt_wT);

    void* args[] = { (void*)&u, (void*)&xproj_w, (void*)&dt_wT, (void*)&dt_b,
                     (void*)&A_log, (void*)&A_im, (void*)&B_param, (void*)&C_param,
                     (void*)&Dp, (void*)&du, (void*)&Pbuf, (void*)&Sbuf,
                     (void*)&Ibuf, (void*)&out };
    hipError_t ce = hipLaunchCooperativeKernel((void*)k_fused, dim3(PBLK),
                                               dim3(256), args, 0, stream);
    if (ce != hipSuccess) {
        (void)hipGetLastError();   // clear sticky error; run proven 4-kernel path
        k_dt<<<Ld / 8, 256, 0, stream>>>(u, xproj_w, dt_wT, dt_b, du);
        dim3 g2(NCHUNK, Hd / 64);
        k_chunk<<<g2, 256, 0, stream>>>(du, A_log, A_im, B_param, Pbuf, Sbuf);
        k_prefix<<<NCH / 256, 256, 0, stream>>>(Pbuf, Sbuf, Ibuf);
        k_scan<<<g2, 256, 0, stream>>>(du, A_log, A_im, B_param, C_param, Dp, Ibuf, out);
    }
}

// Round 3
// 149.729 us; speedup vs baseline: 2.2830x; 2.2830x over previous
//
#include <hip/hip_runtime.h>

#define Hd 512
#define N2d 16
#define Rd 32
#define Ld 4096
#define NCHUNK 256
#define CLEN (Ld / NCHUNK)        // 16
#define NCH (Hd * N2d)            // 8192 chains
#define NGRP 16                   // chunks per prefix group
#define NGROUPS (NCHUNK / NGRP)   // 16

// ---------------------------------------------------------------------------
// Kernel 0: transpose dt_w[H][R] -> dt_wT[R][H] for coalesced einsum2 loads.
// ---------------------------------------------------------------------------
__global__ __launch_bounds__(256) void k_tw(const float* __restrict__ dt_w,
                                            float* __restrict__ dt_wT) {
    int idx = blockIdx.x * 256 + threadIdx.x;   // 0..16383
    int r = idx >> 9;
    int h = idx & 511;
    dt_wT[idx] = dt_w[h * Rd + r];
}

// ---------------------------------------------------------------------------
// Per-thread constant setup: 4 consecutive n of one h. fast == true when Are
// uniform and Aim arithmetic across the 4 (true for S4D init A = -1 + i*n).
// ---------------------------------------------------------------------------
__device__ __forceinline__ bool load_consts4(const float* A_log, const float* A_im,
        const float* B_param, int hnb,
        float* Are, float* Aim, float* BAr, float* BAi) {
    #pragma unroll
    for (int j = 0; j < 4; ++j) {
        int hn = hnb + j;
        Are[j] = -__expf(A_log[hn]);
        Aim[j] = A_im[hn];
        float Bre = B_param[2 * hn];
        float Bim = B_param[2 * hn + 1];
        float inv = __builtin_amdgcn_rcpf(Are[j] * Are[j] + Aim[j] * Aim[j]);
        BAr[j] = (Bre * Are[j] + Bim * Aim[j]) * inv;   // Bc*conj(A)/|A|^2
        BAi[j] = (Bim * Are[j] - Bre * Aim[j]) * inv;
    }
    float d1 = Aim[1] - Aim[0], d2 = Aim[2] - Aim[1], d3 = Aim[3] - Aim[2];
    return (Are[1] == Are[0]) && (Are[2] == Are[0]) && (Are[3] == Are[0]) &&
           (d1 == d2) && (d2 == d3);
}

// ---------------------------------------------------------------------------
// Kernel 1: dt = softplus(u@xprojT@dtwT + b); writes du[l][h] = (dt, u/dt).
// ---------------------------------------------------------------------------
__global__ __launch_bounds__(256) void k_dt(const float* __restrict__ u,
                                            const float* __restrict__ xproj_w,
                                            const float* __restrict__ dt_wT,
                                            const float* __restrict__ dt_b,
                                            float2* __restrict__ du_out) {
    __shared__ float u_s[8][Hd];
    __shared__ float dtu_s[8][Rd];
    const int t = threadIdx.x;
    const int l0 = blockIdx.x * 8;

    #pragma unroll
    for (int i = 0; i < 16; ++i) {
        int idx = t + i * 256;
        ((float*)u_s)[idx] = u[l0 * Hd + idx];
    }
    __syncthreads();

    const int r = t >> 3;
    const int j = t & 7;
    float part[8];
    #pragma unroll
    for (int l = 0; l < 8; ++l) part[l] = 0.f;
    for (int k = 0; k < 64; ++k) {
        float w = xproj_w[r * Hd + k * 8 + j];
        #pragma unroll
        for (int l = 0; l < 8; ++l) part[l] = fmaf(u_s[l][k * 8 + j], w, part[l]);
    }
    #pragma unroll
    for (int off = 1; off < 8; off <<= 1) {
        #pragma unroll
        for (int l = 0; l < 8; ++l) part[l] += __shfl_xor(part[l], off);
    }
    if (j == 0) {
        #pragma unroll
        for (int l = 0; l < 8; ++l) dtu_s[l][r] = part[l];
    }
    __syncthreads();

    #pragma unroll
    for (int hb = 0; hb < 2; ++hb) {
        int h = hb * 256 + t;
        float bias = dt_b[h];
        float acc[8];
        #pragma unroll
        for (int l = 0; l < 8; ++l) acc[l] = bias;
        for (int rr = 0; rr < Rd; ++rr) {
            float w = dt_wT[rr * Hd + h];
            #pragma unroll
            for (int l = 0; l < 8; ++l) acc[l] = fmaf(dtu_s[l][rr], w, acc[l]);
        }
        #pragma unroll
        for (int l = 0; l < 8; ++l) {
            float x = acc[l];
            float sp = fmaxf(x, 0.f) + log1pf(__expf(-fabsf(x)));  // softplus
            float uv = u_s[l][h];
            float us = uv * __builtin_amdgcn_rcpf(fmaxf(sp, 1e-30f));
            du_out[(l0 + l) * Hd + h] = make_float2(sp, us);
        }
    }
}

// ---------------------------------------------------------------------------
// Kernel 2: per-chunk scan (h0=0) -> P (chunk A-product), S (chunk state).
// CLEN=16; the whole chunk's du is prefetched into registers up front so
// load latency overlaps the unrolled compute. Grid (NCHUNK, H/64) = 2048
// blocks -> ~8 blocks/CU capacity (latency hiding was the round-2 limiter).
// ---------------------------------------------------------------------------
__global__ __launch_bounds__(256) void k_chunk(const float2* __restrict__ du,
        const float* __restrict__ A_log, const float* __restrict__ A_im,
        const float* __restrict__ B_param,
        float2* __restrict__ Pbuf, float2* __restrict__ Sbuf) {
    const int t = threadIdx.x;
    const int q = t & 3;
    const int hh = blockIdx.y * 64 + (t >> 2);
    const int c = blockIdx.x;
    const int hnb = hh * N2d + q * 4;
    const int lbase = c * CLEN;

    float2 d[CLEN];
    #pragma unroll
    for (int k = 0; k < CLEN; ++k) d[k] = du[(lbase + k) * Hd + hh];

    float Are[4], Aim[4], BAr[4], BAi[4];
    const bool fast = load_consts4(A_log, A_im, B_param, hnb, Are, Aim, BAr, BAi);
    float sr[4] = {0.f, 0.f, 0.f, 0.f}, si[4] = {0.f, 0.f, 0.f, 0.f};
    float sdt = 0.f;
    if (fast) {
        const float Are0 = Are[0], Aim0 = Aim[0], dA = Aim[1] - Aim[0];
        #pragma unroll
        for (int k = 0; k < CLEN; ++k) {
            float dtv = d[k].x, us = d[k].y;
            sdt += dtv;
            float er = __expf(dtv * Are0);
            float s0, c0, sd, cd;
            __sincosf(dtv * Aim0, &s0, &c0);
            __sincosf(dtv * dA, &sd, &cd);
            float ar = er * c0, ai = er * s0;
            #pragma unroll
            for (int jj = 0; jj < 4; ++jj) {
                float gr = fmaf(ar, us, -us);
                float gi = ai * us;
                float nr = fmaf(ar, sr[jj], fmaf(-ai, si[jj], fmaf(gr, BAr[jj], -gi * BAi[jj])));
                float ni = fmaf(ar, si[jj], fmaf( ai, sr[jj], fmaf(gr, BAi[jj],  gi * BAr[jj])));
                sr[jj] = nr; si[jj] = ni;
                if (jj < 3) {
                    float tr = fmaf(ar, cd, -ai * sd);
                    ai = fmaf(ai, cd, ar * sd);
                    ar = tr;
                }
            }
        }
    } else {
        #pragma unroll
        for (int k = 0; k < CLEN; ++k) {
            float dtv = d[k].x, us = d[k].y;
            sdt += dtv;
            #pragma unroll
            for (int jj = 0; jj < 4; ++jj) {
                float er = __expf(dtv * Are[jj]);
                float s, cc;
                __sincosf(dtv * Aim[jj], &s, &cc);
                float ar = er * cc, ai = er * s;
                float gr = fmaf(ar, us, -us);
                float gi = ai * us;
                float nr = fmaf(ar, sr[jj], fmaf(-ai, si[jj], fmaf(gr, BAr[jj], -gi * BAi[jj])));
                float ni = fmaf(ar, si[jj], fmaf( ai, sr[jj], fmaf(gr, BAi[jj],  gi * BAr[jj])));
                sr[jj] = nr; si[jj] = ni;
            }
        }
    }
    int base = c * NCH + hnb;
    #pragma unroll
    for (int jj = 0; jj < 4; ++jj) {
        float er = __expf(sdt * Are[jj]);
        float s, cc;
        __sincosf(sdt * Aim[jj], &s, &cc);
        Pbuf[base + jj] = make_float2(er * cc, er * s);
        Sbuf[base + jj] = make_float2(sr[jj], si[jj]);
    }
}

// ---------------------------------------------------------------------------
// Kernel 3a: per-group sequential combine (16 chunks per group).
// For each chunk c in its group, writes the EXCLUSIVE in-group prefix state
// Ilocal[c] and the exclusive in-group A-product Pcum[c]; writes group
// aggregates (Gp, Gs). 131072 threads (512 blocks) — fully latency-covered,
// replacing the 128-wave serial k_prefix that stalled the whole GPU.
// ---------------------------------------------------------------------------
__global__ __launch_bounds__(256) void k_group(const float2* __restrict__ Pbuf,
        const float2* __restrict__ Sbuf, float2* __restrict__ Ilocal,
        float2* __restrict__ Pcum, float2* __restrict__ Gp,
        float2* __restrict__ Gs) {
    int idx = blockIdx.x * 256 + threadIdx.x;   // 0..131071
    int chain = idx & (NCH - 1);
    int g = idx >> 13;                          // 0..15
    float pr = 1.f, pi = 0.f, hr = 0.f, hi = 0.f;
    #pragma unroll
    for (int half = 0; half < 2; ++half) {
        float2 tp[8], ts[8];
        #pragma unroll
        for (int i = 0; i < 8; ++i) {
            int c = g * NGRP + half * 8 + i;
            tp[i] = Pbuf[c * NCH + chain];
            ts[i] = Sbuf[c * NCH + chain];
        }
        #pragma unroll
        for (int i = 0; i < 8; ++i) {
            int c = g * NGRP + half * 8 + i;
            Ilocal[c * NCH + chain] = make_float2(hr, hi);
            Pcum[c * NCH + chain]   = make_float2(pr, pi);
            float nhr = fmaf(tp[i].x, hr, fmaf(-tp[i].y, hi, ts[i].x));
            float nhi = fmaf(tp[i].x, hi, fmaf( tp[i].y, hr, ts[i].y));
            float npr = fmaf(tp[i].x, pr, -tp[i].y * pi);
            float npi = fmaf(tp[i].x, pi,  tp[i].y * pr);
            hr = nhr; hi = nhi; pr = npr; pi = npi;
        }
    }
    Gp[g * NCH + chain] = make_float2(pr, pi);
    Gs[g * NCH + chain] = make_float2(hr, hi);
}

// ---------------------------------------------------------------------------
// Kernel 3b: scan the 16 group aggregates per chain -> group-start state H0g.
// Only 8192 threads but only 16 short steps with all loads batched up front.
// ---------------------------------------------------------------------------
__global__ __launch_bounds__(256) void k_gscan(const float2* __restrict__ Gp,
        const float2* __restrict__ Gs, float2* __restrict__ H0g) {
    int chain = blockIdx.x * 256 + threadIdx.x;  // 0..8191
    float2 gp[NGROUPS], gs[NGROUPS];
    #pragma unroll
    for (int g = 0; g < NGROUPS; ++g) {
        gp[g] = Gp[g * NCH + chain];
        gs[g] = Gs[g * NCH + chain];
    }
    float hr = 0.f, hi = 0.f;
    #pragma unroll
    for (int g = 0; g < NGROUPS; ++g) {
        H0g[g * NCH + chain] = make_float2(hr, hi);
        float nr = fmaf(gp[g].x, hr, fmaf(-gp[g].y, hi, gs[g].x));
        float ni = fmaf(gp[g].x, hi, fmaf( gp[g].y, hr, gs[g].y));
        hr = nr; hi = ni;
    }
}

// ---------------------------------------------------------------------------
// Kernel 4: re-scan chunks with correct init; emit y.
// h0[c] = Ilocal[c] + Pcum[c] * H0g[group(c)]  (composed in registers).
// ---------------------------------------------------------------------------
__global__ __launch_bounds__(256) void k_scan(const float2* __restrict__ du,
        const float* __restrict__ A_log, const float* __restrict__ A_im,
        const float* __restrict__ B_param, const float* __restrict__ C_param,
        const float* __restrict__ Dp, const float2* __restrict__ Ilocal,
        const float2* __restrict__ Pcum, const float2* __restrict__ H0g,
        float* __restrict__ out) {
    const int t = threadIdx.x;
    const int q = t & 3;
    const int hh = blockIdx.y * 64 + (t >> 2);
    const int c = blockIdx.x;
    const int g = c / NGRP;
    const int hnb = hh * N2d + q * 4;
    const int lbase = c * CLEN;

    float2 d[CLEN];
    #pragma unroll
    for (int k = 0; k < CLEN; ++k) d[k] = du[(lbase + k) * Hd + hh];

    float Are[4], Aim[4], BAr[4], BAi[4], Cre[4], Cim[4];
    const bool fast = load_consts4(A_log, A_im, B_param, hnb, Are, Aim, BAr, BAi);
    #pragma unroll
    for (int jj = 0; jj < 4; ++jj) {
        Cre[jj] = C_param[2 * (hnb + jj)];
        Cim[jj] = C_param[2 * (hnb + jj) + 1];
    }
    const float Dv = Dp[hh];
    float hr[4], hi[4];
    #pragma unroll
    for (int jj = 0; jj < 4; ++jj) {
        int ch = c * NCH + hnb + jj;
        float2 il = Ilocal[ch];
        float2 pc = Pcum[ch];
        float2 hg = H0g[g * NCH + hnb + jj];
        hr[jj] = fmaf(pc.x, hg.x, fmaf(-pc.y, hg.y, il.x));
        hi[jj] = fmaf(pc.x, hg.y, fmaf( pc.y, hg.x, il.y));
    }

    if (fast) {
        const float Are0 = Are[0], Aim0 = Aim[0], dA = Aim[1] - Aim[0];
        #pragma unroll
        for (int k = 0; k < CLEN; ++k) {
            int l = lbase + k;
            float dtv = d[k].x, us = d[k].y;
            float er = __expf(dtv * Are0);
            float s0, c0, sd, cd;
            __sincosf(dtv * Aim0, &s0, &c0);
            __sincosf(dtv * dA, &sd, &cd);
            float ar = er * c0, ai = er * s0;
            float yv = 0.f;
            #pragma unroll
            for (int jj = 0; jj < 4; ++jj) {
                float gr = fmaf(ar, us, -us);
                float gi = ai * us;
                float nr = fmaf(ar, hr[jj], fmaf(-ai, hi[jj], fmaf(gr, BAr[jj], -gi * BAi[jj])));
                float ni = fmaf(ar, hi[jj], fmaf( ai, hr[jj], fmaf(gr, BAi[jj],  gi * BAr[jj])));
                hr[jj] = nr; hi[jj] = ni;
                yv = fmaf(nr, Cre[jj], fmaf(-ni, Cim[jj], yv));
                if (jj < 3) {
                    float tr = fmaf(ar, cd, -ai * sd);
                    ai = fmaf(ai, cd, ar * sd);
                    ar = tr;
                }
            }
            yv += __shfl_xor(yv, 1);
            yv += __shfl_xor(yv, 2);
            if (q == 0) out[l * Hd + hh] = fmaf(dtv * us, Dv, yv);
        }
    } else {
        #pragma unroll
        for (int k = 0; k < CLEN; ++k) {
            int l = lbase + k;
            float dtv = d[k].x, us = d[k].y;
            float yv = 0.f;
            #pragma unroll
            for (int jj = 0; jj < 4; ++jj) {
                float er = __expf(dtv * Aim[jj] * 0.f + dtv * Are[jj]);  // keep form simple
                float s, cc;
                __sincosf(dtv * Aim[jj], &s, &cc);
                float ar = er * cc, ai = er * s;
                float gr = fmaf(ar, us, -us);
                float gi = ai * us;
                float nr = fmaf(ar, hr[jj], fmaf(-ai, hi[jj], fmaf(gr, BAr[jj], -gi * BAi[jj])));
                float ni = fmaf(ar, hi[jj], fmaf( ai, hr[jj], fmaf(gr, BAi[jj],  gi * BAr[jj])));
                hr[jj] = nr; hi[jj] = ni;
                yv = fmaf(nr, Cre[jj], fmaf(-ni, Cim[jj], yv));
            }
            yv += __shfl_xor(yv, 1);
            yv += __shfl_xor(yv, 2);
            if (q == 0) out[l * Hd + hh] = fmaf(dtv * us, Dv, yv);
        }
    }
}

extern "C" void kernel_launch(void* const* d_in, const int* in_sizes, int n_in,
                              void* d_out, int out_size, void* d_ws, size_t ws_size,
                              hipStream_t stream) {
    const float* u        = (const float*)d_in[0];
    const float* A_log    = (const float*)d_in[1];
    const float* A_im     = (const float*)d_in[2];
    const float* B_param  = (const float*)d_in[3];
    const float* C_param  = (const float*)d_in[4];
    const float* Dp       = (const float*)d_in[5];
    const float* dt_w     = (const float*)d_in[6];
    const float* dt_b     = (const float*)d_in[7];
    const float* xproj_w  = (const float*)d_in[8];

    // ws layout (float2 units):
    // du[L*H] | P[NCHUNK*NCH] | S | Ilocal | Pcum | Gp[16*NCH] | Gs | H0g | dt_wT
    float2* du     = (float2*)d_ws;
    float2* Pbuf   = du + (size_t)Ld * Hd;
    float2* Sbuf   = Pbuf + (size_t)NCHUNK * NCH;
    float2* Ilocal = Sbuf + (size_t)NCHUNK * NCH;
    float2* Pcum   = Ilocal + (size_t)NCHUNK * NCH;
    float2* Gp     = Pcum + (size_t)NCHUNK * NCH;
    float2* Gs     = Gp + (size_t)NGROUPS * NCH;
    float2* H0g    = Gs + (size_t)NGROUPS * NCH;
    float*  dt_wT  = (float*)(H0g + (size_t)NGROUPS * NCH);
    float*  out    = (float*)d_out;

    k_tw<<<(Rd * Hd) / 256, 256, 0, stream>>>(dt_w, dt_wT);
    k_dt<<<Ld / 8, 256, 0, stream>>>(u, xproj_w, dt_wT, dt_b, du);
    dim3 g2(NCHUNK, Hd / 64);
    k_chunk<<<g2, 256, 0, stream>>>(du, A_log, A_im, B_param, Pbuf, Sbuf);
    k_group<<<(NCH * NGROUPS) / 256, 256, 0, stream>>>(Pbuf, Sbuf, Ilocal, Pcum, Gp, Gs);
    k_gscan<<<NCH / 256, 256, 0, stream>>>(Gp, Gs, H0g);
    k_scan<<<g2, 256, 0, stream>>>(du, A_log, A_im, B_param, C_param, Dp,
                                   Ilocal, Pcum, H0g, out);
}